// Round 14
// baseline (556.619 us; speedup 1.0000x reference)
//
#include <hip/hip_runtime.h>

#define N_NODES 100000
#define N_EDGES 3200000
#define F_IN    1433
#define HID     16
#define N_CLS   7
#define CAP     96
#define NWINT   48
#define NWIN    12
#define GB1     (N_NODES / 16)                       // 6250 gemm tiles
#define ROWBLKS ((N_NODES + 255) / 256)              // 391
#define XB_STRIDE 1440                               // padded bf16 row (2880B, 16B-aligned)
#define XB_TOTAL  ((size_t)N_NODES * XB_STRIDE)      // 144,000,000 shorts
#define NF4     (N_NODES * F_IN / 4)                 // 35,825,000 float4s (exact)
#define NGRP    1035                                 // fatprep groups of 5 blocks
#define NREP    (NGRP * 2)                           // 2070 repack blocks
#define NFILL   (NGRP * 3)                           // 3105 fill blocks
#define NQUAD   (N_EDGES / 4)                        // 800,000 edge quads

typedef __attribute__((ext_vector_type(8))) short short8v;
typedef __attribute__((ext_vector_type(4))) float float4v;

__device__ __forceinline__ unsigned short f2bf(float f) {
    unsigned u = __float_as_uint(f);
    u += 0x7fffu + ((u >> 16) & 1u);                 // RNE
    return (unsigned short)(u >> 16);
}

// ---------------- prep: pre-swizzled bf16 W1 fragments ----------------
__global__ void prep_w1_kernel(const float* __restrict__ W1, short* __restrict__ w1f) {
    int w = blockIdx.x;
    int l = threadIdx.x;
    int col = l & 15;
    int kb = w * 32 + (l >> 4) * 8;
    short8v f;
#pragma unroll
    for (int i = 0; i < 8; ++i) {
        int k = kb + i;
        float v = (k < F_IN) ? W1[k * HID + col] : 0.f;
        f[i] = (short)f2bf(v);
    }
    *(short8v*)(w1f + ((size_t)w * 64 + l) * 8) = f;
}

// ---------------- fat: x->bf16 repack ++ ELL fill, INTERLEAVED ----------------
// Per 5-block group: 2 repack + 3 fill -> every CU holds a mix at all times,
// so fill's atomic/latency waits hide under repack's BW streaming (R13: the
// 2048-block repack occupied the whole GPU first; fill ran serially after).

__global__ __launch_bounds__(256) void fatprep_kernel(const float* __restrict__ x,
                                                      short* __restrict__ xb,
                                                      const int* __restrict__ src,
                                                      const int* __restrict__ dst,
                                                      int* __restrict__ cur,
                                                      int* __restrict__ ell) {
    const int bid = blockIdx.x;
    const int grp = bid / 5, r = bid % 5;
    if (r < 2) {
        // ---- repack path (grid-stride over NREP virtual blocks) ----
        const int rb = grp * 2 + r;
        for (long i4 = (long)rb * 256 + threadIdx.x; i4 < NF4; i4 += (long)NREP * 256) {
            float4 v = ((const float4*)x)[i4];
            float fv[4] = {v.x, v.y, v.z, v.w};
            unsigned e0 = (unsigned)(i4 * 4);
#pragma unroll
            for (int j = 0; j < 4; ++j) {
                unsigned e = e0 + j;
                unsigned row = e / 1433u;             // magic-mul
                unsigned col = e - row * 1433u;
                xb[(size_t)row * XB_STRIDE + col] = (short)f2bf(fv[j]);
            }
        }
        for (int p = rb * 256 + threadIdx.x; p < N_NODES * 7; p += NREP * 256) {
            int row = p / 7;
            int col = 1433 + (p - row * 7);
            xb[(size_t)row * XB_STRIDE + col] = 0;
        }
        return;
    }
    // ---- ELL fill path (grid-stride over NFILL virtual blocks) ----
    const int fb = grp * 3 + (r - 2);
    for (int i = fb * 256 + threadIdx.x; i < NQUAD; i += NFILL * 256) {
        int4 s4 = ((const int4*)src)[i];
        int4 d4 = ((const int4*)dst)[i];
        int p;
        p = atomicAdd(&cur[d4.x], 1); if (p < CAP) ell[(size_t)d4.x * CAP + p] = s4.x;
        p = atomicAdd(&cur[d4.y], 1); if (p < CAP) ell[(size_t)d4.y * CAP + p] = s4.y;
        p = atomicAdd(&cur[d4.z], 1); if (p < CAP) ell[(size_t)d4.z * CAP + p] = s4.z;
        p = atomicAdd(&cur[d4.w], 1); if (p < CAP) ell[(size_t)d4.w * CAP + p] = s4.w;
    }
}

// ---------------- layer 1: t1 = xb @ W1, low-VGPR pipelined MFMA ------------
// af software-pipelined 3-deep (12 VGPR); bf loaded per-window from hot L1/L2
// w1f (48KB). Target VGPR <= 64 -> 32 waves/CU -> 3x outstanding lines vs
// R13's VGPR-128 version (R12 lesson: gemm BW = occupancy x in-flight lines).
// __launch_bounds__(256) essential (R10: spill disaster without it).

__global__ __launch_bounds__(256) void gemm1_kernel(const short* __restrict__ xb,
                                                    const short* __restrict__ w1f,
                                                    float* __restrict__ t1) {
    __shared__ float red[4][256];
    const int tid = threadIdx.x;
    const int s = tid >> 6;                // wave / K-slice
    const int l = tid & 63;                // lane
    const int R0 = blockIdx.x * 16;
    const int g = l >> 4;                  // k-group
    const int c = l & 15;                  // A row / B col
    const int row = R0 + c;
    const size_t base = (size_t)row * XB_STRIDE + g * 8;
    const short* __restrict__ wfp = w1f + ((size_t)(s * NWIN) * 64 + l) * 8;

    short8v a[3];
#pragma unroll
    for (int wl = 0; wl < 3; ++wl) {       // prologue: 3-deep af pipeline
        size_t off = base + (size_t)(s * NWIN + wl) * 32;
        if (off > XB_TOTAL - 8) off = XB_TOTAL - 8;
        a[wl] = *(const short8v*)(xb + off);
    }

    float4v acc = {0.f, 0.f, 0.f, 0.f};
#pragma unroll
    for (int wl = 0; wl < NWIN; ++wl) {
        short8v bfv = *(const short8v*)(wfp + (size_t)wl * 512);
        short8v av = a[wl % 3];            // static index (full unroll)
        if (wl + 3 < NWIN) {
            size_t off = base + (size_t)(s * NWIN + wl + 3) * 32;
            if (off > XB_TOTAL - 8) off = XB_TOTAL - 8;
            a[wl % 3] = *(const short8v*)(xb + off);
        }
        acc = __builtin_amdgcn_mfma_f32_16x16x32_bf16(av, bfv, acc, 0, 0, 0);
    }

    // cross-wave K reduction (D map: col=l&15, row=4*(l>>4)+j — verified)
#pragma unroll
    for (int j = 0; j < 4; ++j) red[s][l * 4 + j] = acc[j];
    __syncthreads();
    {
        int rr = tid >> 4, cc = tid & 15;
        int idx = ((rr >> 2) * 16 + cc) * 4 + (rr & 3);
        float vv = red[0][idx] + red[1][idx] + red[2][idx] + red[3][idx];
        t1[(long)(R0 + rr) * HID + cc] = vv;
    }
}

// h = relu(gather-sum(t1) + t1 + b1); 4 lanes per node, float4 gathers
__global__ void agg1_kernel(const float* __restrict__ t1, const int* __restrict__ cur,
                            const int* __restrict__ ell, const float* __restrict__ b1,
                            float* __restrict__ h) {
    int tid = blockIdx.x * blockDim.x + threadIdx.x;
    if (tid >= N_NODES * 4) return;
    int node = tid >> 2;
    int q = tid & 3;
    int d = cur[node]; if (d > CAP) d = CAP;
    const int* el = ell + (size_t)node * CAP;
    float4 a = *(const float4*)(t1 + ((size_t)node * 16 + q * 4));
    float4 b = *(const float4*)(b1 + q * 4);
    a.x += b.x; a.y += b.y; a.z += b.z; a.w += b.w;
    for (int e = 0; e < d; ++e) {
        int s = el[e];
        float4 v = *(const float4*)(t1 + ((size_t)s * 16 + q * 4));
        a.x += v.x; a.y += v.y; a.z += v.z; a.w += v.w;
    }
    float4 r = {fmaxf(a.x, 0.f), fmaxf(a.y, 0.f), fmaxf(a.z, 0.f), fmaxf(a.w, 0.f)};
    *(float4*)(h + ((size_t)node * 16 + q * 4)) = r;
}

// ---------------- layer 2 (t2 padded to stride 8) ----------------

__global__ void gemm2_kernel(const float* __restrict__ h, const float* __restrict__ W2,
                             float* __restrict__ t2p) {
    int node = blockIdx.x * blockDim.x + threadIdx.x;
    if (node >= N_NODES) return;
    const float4* hr = (const float4*)(h + (size_t)node * HID);
    float hv[HID];
    ((float4*)hv)[0] = hr[0];
    ((float4*)hv)[1] = hr[1];
    ((float4*)hv)[2] = hr[2];
    ((float4*)hv)[3] = hr[3];
    float o8[8];
#pragma unroll
    for (int cNum = 0; cNum < N_CLS; ++cNum) {
        float a = 0.f;
#pragma unroll
        for (int j = 0; j < HID; ++j) a = fmaf(hv[j], W2[j * N_CLS + cNum], a);
        o8[cNum] = a;
    }
    o8[7] = 0.f;
    float4* op = (float4*)(t2p + (size_t)node * 8);
    op[0] = ((float4*)o8)[0];
    op[1] = ((float4*)o8)[1];
}

// out = gather-sum(t2) + t2 + b2; 2 lanes per node, float4 gathers
__global__ void agg2_kernel(const float* __restrict__ t2p, const int* __restrict__ cur,
                            const int* __restrict__ ell, const float* __restrict__ b2,
                            float* __restrict__ out) {
    int tid = blockIdx.x * blockDim.x + threadIdx.x;
    if (tid >= N_NODES * 2) return;
    int node = tid >> 1;
    int q = tid & 1;
    int d = cur[node]; if (d > CAP) d = CAP;
    const int* el = ell + (size_t)node * CAP;
    float4 a = *(const float4*)(t2p + ((size_t)node * 8 + q * 4));
    if (q == 0) {
        a.x += b2[0]; a.y += b2[1]; a.z += b2[2]; a.w += b2[3];
    } else {
        a.x += b2[4]; a.y += b2[5]; a.z += b2[6];
    }
    for (int e = 0; e < d; ++e) {
        int s = el[e];
        float4 v = *(const float4*)(t2p + ((size_t)s * 8 + q * 4));
        a.x += v.x; a.y += v.y; a.z += v.z; a.w += v.w;
    }
    float* op = out + (size_t)node * 7 + q * 4;
    op[0] = a.x; op[1] = a.y; op[2] = a.z;
    if (q == 0) op[3] = a.w;
}

// ---------------- launch ----------------

extern "C" void kernel_launch(void* const* d_in, const int* in_sizes, int n_in,
                              void* d_out, int out_size, void* d_ws, size_t ws_size,
                              hipStream_t stream) {
    const float* x  = (const float*)d_in[0];
    const int*   ei = (const int*)d_in[1];
    const float* W1 = (const float*)d_in[2];
    const float* b1 = (const float*)d_in[3];
    const float* W2 = (const float*)d_in[4];
    const float* b2 = (const float*)d_in[5];
    const int* src = ei;
    const int* dst = ei + N_EDGES;
    float* out = (float*)d_out;

    char* w = (char*)d_ws;
    float* t1  = (float*)w;  w += (size_t)N_NODES * HID * sizeof(float);
    float* h   = (float*)w;  w += (size_t)N_NODES * HID * sizeof(float);
    float* t2p = (float*)w;  w += (size_t)N_NODES * 8 * sizeof(float);
    int* cur   = (int*)w;    w += (size_t)N_NODES * sizeof(int);
    short* w1f = (short*)w;  w += (size_t)NWINT * 64 * 8 * sizeof(short);
    short* xb  = (short*)w;  w += XB_TOTAL * sizeof(short) + 256;  // +slack (clamped reads)
    int* ell   = (int*)w;    w += (size_t)N_NODES * CAP * sizeof(int);

    hipMemsetAsync(cur, 0, (size_t)N_NODES * sizeof(int), stream);
    prep_w1_kernel<<<NWINT, 64, 0, stream>>>(W1, w1f);

    // x->bf16 repack ++ ELL fill, interleaved 2:3 per 5-block group
    fatprep_kernel<<<NGRP * 5, 256, 0, stream>>>(x, xb, src, dst, cur, ell);

    gemm1_kernel<<<GB1, 256, 0, stream>>>(xb, w1f, t1);
    agg1_kernel<<<(N_NODES * 4 + 255) / 256, 256, 0, stream>>>(t1, cur, ell, b1, h);
    gemm2_kernel<<<ROWBLKS, 256, 0, stream>>>(h, W2, t2p);
    agg2_kernel<<<(N_NODES * 2 + 255) / 256, 256, 0, stream>>>(t2p, cur, ell, b2, out);
}

// Round 15
// 446.128 us; speedup vs baseline: 1.2477x; 1.2477x over previous
//
#include <hip/hip_runtime.h>

#define N_NODES 100000
#define N_EDGES 3200000
#define F_IN    1433
#define HID     16
#define N_CLS   7
#define CAP     96                                   // ELL capacity; Poisson(32) tail @96 ~ 1e-18
#define NWINT   48                                   // K windows of 32 (K padded to 1536)
#define NWIN    12                                   // windows per wave (4 waves)
#define GB1     (N_NODES / 16)                       // 6250 gemm tiles of 16 rows (exact)
#define EB      (N_EDGES / 4 / 256)                  // 3125 edge-fill blocks
#define ROWBLKS ((N_NODES + 255) / 256)              // 391

typedef __attribute__((ext_vector_type(8))) short short8v;
typedef __attribute__((ext_vector_type(4))) float float4v;

__device__ __forceinline__ unsigned short f2bf(float f) {
    unsigned u = __float_as_uint(f);
    u += 0x7fffu + ((u >> 16) & 1u);                 // RNE
    return (unsigned short)(u >> 16);
}

// ---------------- prep: pre-swizzled bf16 W1 fragments ----------------
// w1f[(w*64+l)*8+i] = bf16(W1[k][col]), k=w*32+(l>>4)*8+i, col=l&15; zero past
// F_IN. 48KB, L2-resident; one dwordx4 per window fetches a wave's B-frag.

__global__ void prep_w1_kernel(const float* __restrict__ W1, short* __restrict__ w1f) {
    int w = blockIdx.x;
    int l = threadIdx.x;
    int col = l & 15;
    int kb = w * 32 + (l >> 4) * 8;
    short8v f;
#pragma unroll
    for (int i = 0; i < 8; ++i) {
        int k = kb + i;
        float v = (k < F_IN) ? W1[k * HID + col] : 0.f;
        f[i] = (short)f2bf(v);
    }
    *(short8v*)(w1f + ((size_t)w * 64 + l) * 8) = f;
}

// ---------------- fat kernel: gemm1 (first) ++ ELL fill (tail) ----------------
// gemm path reads x DIRECTLY (no repack pass): staging instr j reads flat
// f = j*64+lane -> rows {2j,2j+1}, two dense 128B segments (the lane-scattered
// staging of R6/R8/R12 was the 0.9-1.4TB/s root cause). Cross-lane redistribute
// via wave-private LDS (lockstep-ordered, R6-proven), bf16-packed, row stride
// 40 shorts (80B) so frag ds_read_b128 is ~conflict-free. W1 frags from w1f.
// Fill blocks dispatch last -> run in the gemm's tail shadow (R8 topology;
// R14 proved interleave hurts, R9 proved fill-first hurts).

__global__ __launch_bounds__(256) void fat1_kernel(const float* __restrict__ x,
                                                   const short* __restrict__ w1f,
                                                   float* __restrict__ t1,
                                                   const int* __restrict__ src,
                                                   const int* __restrict__ dst,
                                                   int* __restrict__ cur,
                                                   int* __restrict__ ell) {
    const int bid = blockIdx.x;
    if (bid >= GB1) {
        // ---- ELL fill path ----
        int i = (bid - GB1) * 256 + threadIdx.x;
        if (i < N_EDGES / 4) {
            int4 s4 = ((const int4*)src)[i];
            int4 d4 = ((const int4*)dst)[i];
            int p;
            p = atomicAdd(&cur[d4.x], 1); if (p < CAP) ell[(size_t)d4.x * CAP + p] = s4.x;
            p = atomicAdd(&cur[d4.y], 1); if (p < CAP) ell[(size_t)d4.y * CAP + p] = s4.y;
            p = atomicAdd(&cur[d4.z], 1); if (p < CAP) ell[(size_t)d4.z * CAP + p] = s4.z;
            p = atomicAdd(&cur[d4.w], 1); if (p < CAP) ell[(size_t)d4.w * CAP + p] = s4.w;
        }
        return;
    }
    // ---- gemm1 path ----
    __shared__ short xs[4][16][40];        // per-wave staging, 80B row stride
    __shared__ float red[4][256];
    const int tid = threadIdx.x;
    const int s = tid >> 6;                // wave / K-slice
    const int l = tid & 63;                // lane
    const int R0 = bid * 16;
    const int g = l >> 4;                  // k-group
    const int c = l & 15;                  // A row / B col
    const int half = l >> 5;               // loader: row parity
    const int col = l & 31;                // loader: col within window
    const short* __restrict__ wfp = w1f + ((size_t)(s * NWIN) * 64 + l) * 8;

    float4v acc = {0.f, 0.f, 0.f, 0.f};
#pragma unroll
    for (int wl = 0; wl < NWIN; ++wl) {
        const int wi = s * NWIN + wl;
        const int kw = wi * 32;
        if (kw < F_IN) {                   // wave-uniform (only wave 3 skips)
            if (kw + 32 <= F_IN) {         // full window
#pragma unroll
                for (int j = 0; j < 8; ++j) {
                    int row = 2 * j + half;
                    float v = x[(size_t)(R0 + row) * F_IN + kw + col];
                    xs[s][row][col] = (short)f2bf(v);
                }
            } else {                       // partial window (wi==44, 25 cols)
#pragma unroll
                for (int j = 0; j < 8; ++j) {
                    int row = 2 * j + half;
                    float v = (kw + col < F_IN)
                                  ? x[(size_t)(R0 + row) * F_IN + kw + col] : 0.f;
                    xs[s][row][col] = (short)f2bf(v);
                }
            }
            // wave-private LDS: lockstep + in-order DS pipe => no barrier
            short8v af = *(const short8v*)&xs[s][c][g * 8];
            short8v bfv = *(const short8v*)(wfp + (size_t)wl * 512);
            acc = __builtin_amdgcn_mfma_f32_16x16x32_bf16(af, bfv, acc, 0, 0, 0);
        }
    }

    // cross-wave K reduction (D map: col=l&15, row=4*(l>>4)+j — verified R6+)
#pragma unroll
    for (int j = 0; j < 4; ++j) red[s][l * 4 + j] = acc[j];
    __syncthreads();
    {
        int r = tid >> 4, cc = tid & 15;
        int idx = ((r >> 2) * 16 + cc) * 4 + (r & 3);
        float vv = red[0][idx] + red[1][idx] + red[2][idx] + red[3][idx];
        t1[(long)(R0 + r) * HID + cc] = vv;
    }
}

// h = relu(gather-sum(t1) + t1 + b1); 4 lanes per node, float4 gathers
__global__ void agg1_kernel(const float* __restrict__ t1, const int* __restrict__ cur,
                            const int* __restrict__ ell, const float* __restrict__ b1,
                            float* __restrict__ h) {
    int tid = blockIdx.x * blockDim.x + threadIdx.x;
    if (tid >= N_NODES * 4) return;
    int node = tid >> 2;
    int q = tid & 3;
    int d = cur[node]; if (d > CAP) d = CAP;
    const int* el = ell + (size_t)node * CAP;
    float4 a = *(const float4*)(t1 + ((size_t)node * 16 + q * 4));
    float4 b = *(const float4*)(b1 + q * 4);
    a.x += b.x; a.y += b.y; a.z += b.z; a.w += b.w;
    for (int e = 0; e < d; ++e) {
        int s = el[e];
        float4 v = *(const float4*)(t1 + ((size_t)s * 16 + q * 4));
        a.x += v.x; a.y += v.y; a.z += v.z; a.w += v.w;
    }
    float4 r = {fmaxf(a.x, 0.f), fmaxf(a.y, 0.f), fmaxf(a.z, 0.f), fmaxf(a.w, 0.f)};
    *(float4*)(h + ((size_t)node * 16 + q * 4)) = r;
}

// ---------------- layer 2 (t2 padded to stride 8) ----------------

__global__ void gemm2_kernel(const float* __restrict__ h, const float* __restrict__ W2,
                             float* __restrict__ t2p) {
    int node = blockIdx.x * blockDim.x + threadIdx.x;
    if (node >= N_NODES) return;
    const float4* hr = (const float4*)(h + (size_t)node * HID);
    float hv[HID];
    ((float4*)hv)[0] = hr[0];
    ((float4*)hv)[1] = hr[1];
    ((float4*)hv)[2] = hr[2];
    ((float4*)hv)[3] = hr[3];
    float o8[8];
#pragma unroll
    for (int cNum = 0; cNum < N_CLS; ++cNum) {
        float a = 0.f;
#pragma unroll
        for (int j = 0; j < HID; ++j) a = fmaf(hv[j], W2[j * N_CLS + cNum], a);
        o8[cNum] = a;
    }
    o8[7] = 0.f;
    float4* op = (float4*)(t2p + (size_t)node * 8);
    op[0] = ((float4*)o8)[0];
    op[1] = ((float4*)o8)[1];
}

// out = gather-sum(t2) + t2 + b2; 2 lanes per node, float4 gathers
__global__ void agg2_kernel(const float* __restrict__ t2p, const int* __restrict__ cur,
                            const int* __restrict__ ell, const float* __restrict__ b2,
                            float* __restrict__ out) {
    int tid = blockIdx.x * blockDim.x + threadIdx.x;
    if (tid >= N_NODES * 2) return;
    int node = tid >> 1;
    int q = tid & 1;
    int d = cur[node]; if (d > CAP) d = CAP;
    const int* el = ell + (size_t)node * CAP;
    float4 a = *(const float4*)(t2p + ((size_t)node * 8 + q * 4));
    if (q == 0) {
        a.x += b2[0]; a.y += b2[1]; a.z += b2[2]; a.w += b2[3];
    } else {
        a.x += b2[4]; a.y += b2[5]; a.z += b2[6];
    }
    for (int e = 0; e < d; ++e) {
        int s = el[e];
        float4 v = *(const float4*)(t2p + ((size_t)s * 8 + q * 4));
        a.x += v.x; a.y += v.y; a.z += v.z; a.w += v.w;
    }
    float* op = out + (size_t)node * 7 + q * 4;
    op[0] = a.x; op[1] = a.y; op[2] = a.z;
    if (q == 0) op[3] = a.w;
}

// ---------------- launch ----------------

extern "C" void kernel_launch(void* const* d_in, const int* in_sizes, int n_in,
                              void* d_out, int out_size, void* d_ws, size_t ws_size,
                              hipStream_t stream) {
    const float* x  = (const float*)d_in[0];
    const int*   ei = (const int*)d_in[1];
    const float* W1 = (const float*)d_in[2];
    const float* b1 = (const float*)d_in[3];
    const float* W2 = (const float*)d_in[4];
    const float* b2 = (const float*)d_in[5];
    const int* src = ei;
    const int* dst = ei + N_EDGES;
    float* out = (float*)d_out;

    char* w = (char*)d_ws;
    float* t1  = (float*)w;  w += (size_t)N_NODES * HID * sizeof(float);
    float* h   = (float*)w;  w += (size_t)N_NODES * HID * sizeof(float);
    float* t2p = (float*)w;  w += (size_t)N_NODES * 8 * sizeof(float);
    int* cur   = (int*)w;    w += (size_t)N_NODES * sizeof(int);
    short* w1f = (short*)w;  w += (size_t)NWINT * 64 * 8 * sizeof(short);
    int* ell   = (int*)w;    w += (size_t)N_NODES * CAP * sizeof(int);

    hipMemsetAsync(cur, 0, (size_t)N_NODES * sizeof(int), stream);
    prep_w1_kernel<<<NWINT, 64, 0, stream>>>(W1, w1f);

    // gemm1 direct-from-x (first) ++ ELL fill (tail-overlapped)
    fat1_kernel<<<GB1 + EB, 256, 0, stream>>>(x, w1f, t1, src, dst, cur, ell);

    agg1_kernel<<<(N_NODES * 4 + 255) / 256, 256, 0, stream>>>(t1, cur, ell, b1, h);
    gemm2_kernel<<<ROWBLKS, 256, 0, stream>>>(h, W2, t2p);
    agg2_kernel<<<(N_NODES * 2 + 255) / 256, 256, 0, stream>>>(t2p, cur, ell, b2, out);
}

// Round 16
// 410.340 us; speedup vs baseline: 1.3565x; 1.0872x over previous
//
#include <hip/hip_runtime.h>

#define N_NODES 100000
#define N_EDGES 3200000
#define F_IN    1433
#define HID     16
#define N_CLS   7
#define CAP     96                                   // ELL capacity; Poisson(32) tail @96 ~ 1e-18
#define NWINT   48                                   // K windows of 32 (K padded to 1536)
#define NWIN    12                                   // windows per wave (4 waves)
#define GB1     (N_NODES / 16)                       // 6250 gemm tiles of 16 rows (exact)
#define EB      (N_EDGES / 4 / 256)                  // 3125 edge-fill blocks
#define ROWBLKS ((N_NODES + 255) / 256)              // 391
#define NTOT    (N_NODES * F_IN)                     // 143,300,000 (< 2^31)

typedef __attribute__((ext_vector_type(8))) short short8v;
typedef __attribute__((ext_vector_type(4))) float float4v;

__device__ __forceinline__ unsigned short f2bf(float f) {
    unsigned u = __float_as_uint(f);
    u += 0x7fffu + ((u >> 16) & 1u);                 // RNE
    return (unsigned short)(u >> 16);
}

// ---------------- prep: pre-swizzled bf16 W1 fragments ----------------
// w1f[(w*64+l)*8+i] = bf16(W1[k][col]), k=w*32+(l>>4)*8+i, col=l&15; ZERO for
// k>=F_IN (this also nullifies gemm's harmless over-reads past row end).

__global__ void prep_w1_kernel(const float* __restrict__ W1, short* __restrict__ w1f) {
    int w = blockIdx.x;
    int l = threadIdx.x;
    int col = l & 15;
    int kb = w * 32 + (l >> 4) * 8;
    short8v f;
#pragma unroll
    for (int i = 0; i < 8; ++i) {
        int k = kb + i;
        float v = (k < F_IN) ? W1[k * HID + col] : 0.f;
        f[i] = (short)f2bf(v);
    }
    *(short8v*)(w1f + ((size_t)w * 64 + l) * 8) = f;
}

// ---------------- fat kernel: gemm1 (first) ++ col-major ELL fill (tail) ----
// gemm: R12 depth x R15 coalescing — ALL 96 x-loads straight-line into
// registers (VGPR~128, launch_bounds(256) essential per R10), each instr
// covering rows {2j,2j+1} x 32 cols = 2 dense 128B lines. Then per-window
// LDS redistribute (wave-private, in-order DS pipe, R6-proven) + MFMA.
// Over-reads past a row's end hit k>=1433 => B-frag is zero => product 0.
// Fill: COLUMN-major ELL ell[slot*N+node] — active write window ~45 planes
// x 400KB fits L2, so scatter write-amp ~1 (R15 row-major: 200MB dirty).

__global__ __launch_bounds__(256) void fat1_kernel(const float* __restrict__ x,
                                                   const short* __restrict__ w1f,
                                                   float* __restrict__ t1,
                                                   const int* __restrict__ src,
                                                   const int* __restrict__ dst,
                                                   int* __restrict__ cur,
                                                   int* __restrict__ ell) {
    const int bid = blockIdx.x;
    if (bid >= GB1) {
        // ---- ELL fill path (column-major) ----
        int i = (bid - GB1) * 256 + threadIdx.x;
        if (i < N_EDGES / 4) {
            int4 s4 = ((const int4*)src)[i];
            int4 d4 = ((const int4*)dst)[i];
            int p;
            p = atomicAdd(&cur[d4.x], 1); if (p < CAP) ell[(size_t)p * N_NODES + d4.x] = s4.x;
            p = atomicAdd(&cur[d4.y], 1); if (p < CAP) ell[(size_t)p * N_NODES + d4.y] = s4.y;
            p = atomicAdd(&cur[d4.z], 1); if (p < CAP) ell[(size_t)p * N_NODES + d4.z] = s4.z;
            p = atomicAdd(&cur[d4.w], 1); if (p < CAP) ell[(size_t)p * N_NODES + d4.w] = s4.w;
        }
        return;
    }
    // ---- gemm1 path ----
    __shared__ short xs[4][16][40];        // per-wave staging, 80B row stride
    __shared__ float red[4][256];
    const int tid = threadIdx.x;
    const int s = tid >> 6;                // wave / K-slice
    const int l = tid & 63;                // lane
    const int R0 = bid * 16;
    const int g = l >> 4;                  // k-group
    const int c = l & 15;                  // A row / B col
    const int half = l >> 5;               // loader: row parity
    const int col = l & 31;                // loader: col within window
    const short* __restrict__ wfp = w1f + ((size_t)(s * NWIN) * 64 + l) * 8;

    // stage ALL windows into registers, straight-line, coalesced
    float v[NWIN][8];
    if (bid != GB1 - 1) {                  // fast arm: unguarded
#pragma unroll
        for (int wl = 0; wl < NWIN; ++wl) {
            int kw = (s * NWIN + wl) * 32;
#pragma unroll
            for (int j = 0; j < 8; ++j)
                v[wl][j] = x[(size_t)((R0 + 2 * j + half) * F_IN + kw + col)];
        }
    } else {                               // final tile: clamp flat index
#pragma unroll
        for (int wl = 0; wl < NWIN; ++wl) {
            int kw = (s * NWIN + wl) * 32;
#pragma unroll
            for (int j = 0; j < 8; ++j) {
                int gi = (R0 + 2 * j + half) * F_IN + kw + col;
                if (gi > NTOT - 1) gi = NTOT - 1;
                v[wl][j] = x[gi];
            }
        }
    }

    float4v acc = {0.f, 0.f, 0.f, 0.f};
#pragma unroll
    for (int wl = 0; wl < NWIN; ++wl) {
#pragma unroll
        for (int j = 0; j < 8; ++j)
            xs[s][2 * j + half][col] = (short)f2bf(v[wl][j]);
        // wave-private LDS, in-order DS pipe: no barrier needed
        short8v af = *(const short8v*)&xs[s][c][g * 8];
        short8v bfv = *(const short8v*)(wfp + (size_t)wl * 512);
        acc = __builtin_amdgcn_mfma_f32_16x16x32_bf16(af, bfv, acc, 0, 0, 0);
    }

    // cross-wave K reduction (D map: col=l&15, row=4*(l>>4)+j — verified R6+)
#pragma unroll
    for (int j = 0; j < 4; ++j) red[s][l * 4 + j] = acc[j];
    __syncthreads();
    {
        int r = tid >> 4, cc = tid & 15;
        int idx = ((r >> 2) * 16 + cc) * 4 + (r & 3);
        float vv = red[0][idx] + red[1][idx] + red[2][idx] + red[3][idx];
        t1[(long)(R0 + r) * HID + cc] = vv;
    }
}

// h = relu(gather-sum(t1) + t1 + b1); 4 lanes/node; col-major ELL reads:
// 16 consecutive nodes/wave share one 64B line per slot e.
__global__ void agg1_kernel(const float* __restrict__ t1, const int* __restrict__ cur,
                            const int* __restrict__ ell, const float* __restrict__ b1,
                            float* __restrict__ h) {
    int tid = blockIdx.x * blockDim.x + threadIdx.x;
    if (tid >= N_NODES * 4) return;
    int node = tid >> 2;
    int q = tid & 3;
    int d = cur[node]; if (d > CAP) d = CAP;
    float4 a = *(const float4*)(t1 + ((size_t)node * 16 + q * 4));
    float4 b = *(const float4*)(b1 + q * 4);
    a.x += b.x; a.y += b.y; a.z += b.z; a.w += b.w;
    for (int e = 0; e < d; ++e) {
        int s = ell[(size_t)e * N_NODES + node];
        float4 v = *(const float4*)(t1 + ((size_t)s * 16 + q * 4));
        a.x += v.x; a.y += v.y; a.z += v.z; a.w += v.w;
    }
    float4 r = {fmaxf(a.x, 0.f), fmaxf(a.y, 0.f), fmaxf(a.z, 0.f), fmaxf(a.w, 0.f)};
    *(float4*)(h + ((size_t)node * 16 + q * 4)) = r;
}

// ---------------- layer 2 (t2 padded to stride 8) ----------------

__global__ void gemm2_kernel(const float* __restrict__ h, const float* __restrict__ W2,
                             float* __restrict__ t2p) {
    int node = blockIdx.x * blockDim.x + threadIdx.x;
    if (node >= N_NODES) return;
    const float4* hr = (const float4*)(h + (size_t)node * HID);
    float hv[HID];
    ((float4*)hv)[0] = hr[0];
    ((float4*)hv)[1] = hr[1];
    ((float4*)hv)[2] = hr[2];
    ((float4*)hv)[3] = hr[3];
    float o8[8];
#pragma unroll
    for (int cNum = 0; cNum < N_CLS; ++cNum) {
        float a = 0.f;
#pragma unroll
        for (int j = 0; j < HID; ++j) a = fmaf(hv[j], W2[j * N_CLS + cNum], a);
        o8[cNum] = a;
    }
    o8[7] = 0.f;
    float4* op = (float4*)(t2p + (size_t)node * 8);
    op[0] = ((float4*)o8)[0];
    op[1] = ((float4*)o8)[1];
}

// out = gather-sum(t2) + t2 + b2; 2 lanes/node; col-major ELL reads
__global__ void agg2_kernel(const float* __restrict__ t2p, const int* __restrict__ cur,
                            const int* __restrict__ ell, const float* __restrict__ b2,
                            float* __restrict__ out) {
    int tid = blockIdx.x * blockDim.x + threadIdx.x;
    if (tid >= N_NODES * 2) return;
    int node = tid >> 1;
    int q = tid & 1;
    int d = cur[node]; if (d > CAP) d = CAP;
    float4 a = *(const float4*)(t2p + ((size_t)node * 8 + q * 4));
    if (q == 0) {
        a.x += b2[0]; a.y += b2[1]; a.z += b2[2]; a.w += b2[3];
    } else {
        a.x += b2[4]; a.y += b2[5]; a.z += b2[6];
    }
    for (int e = 0; e < d; ++e) {
        int s = ell[(size_t)e * N_NODES + node];
        float4 v = *(const float4*)(t2p + ((size_t)s * 8 + q * 4));
        a.x += v.x; a.y += v.y; a.z += v.z; a.w += v.w;
    }
    float* op = out + (size_t)node * 7 + q * 4;
    op[0] = a.x; op[1] = a.y; op[2] = a.z;
    if (q == 0) op[3] = a.w;
}

// ---------------- launch ----------------

extern "C" void kernel_launch(void* const* d_in, const int* in_sizes, int n_in,
                              void* d_out, int out_size, void* d_ws, size_t ws_size,
                              hipStream_t stream) {
    const float* x  = (const float*)d_in[0];
    const int*   ei = (const int*)d_in[1];
    const float* W1 = (const float*)d_in[2];
    const float* b1 = (const float*)d_in[3];
    const float* W2 = (const float*)d_in[4];
    const float* b2 = (const float*)d_in[5];
    const int* src = ei;
    const int* dst = ei + N_EDGES;
    float* out = (float*)d_out;

    char* w = (char*)d_ws;
    float* t1  = (float*)w;  w += (size_t)N_NODES * HID * sizeof(float);
    float* h   = (float*)w;  w += (size_t)N_NODES * HID * sizeof(float);
    float* t2p = (float*)w;  w += (size_t)N_NODES * 8 * sizeof(float);
    int* cur   = (int*)w;    w += (size_t)N_NODES * sizeof(int);
    short* w1f = (short*)w;  w += (size_t)NWINT * 64 * 8 * sizeof(short);
    int* ell   = (int*)w;    w += (size_t)CAP * N_NODES * sizeof(int);

    hipMemsetAsync(cur, 0, (size_t)N_NODES * sizeof(int), stream);
    prep_w1_kernel<<<NWINT, 64, 0, stream>>>(W1, w1f);

    // gemm1 (first) ++ col-major ELL fill (tail-overlapped)
    fat1_kernel<<<GB1 + EB, 256, 0, stream>>>(x, w1f, t1, src, dst, cur, ell);

    agg1_kernel<<<(N_NODES * 4 + 255) / 256, 256, 0, stream>>>(t1, cur, ell, b1, h);
    gemm2_kernel<<<ROWBLKS, 256, 0, stream>>>(h, W2, t2p);
    agg2_kernel<<<(N_NODES * 2 + 255) / 256, 256, 0, stream>>>(t2p, cur, ell, b2, out);
}